// Round 6
// baseline (3083.082 us; speedup 1.0000x reference)
//
#include <hip/hip_runtime.h>
#include <hip/hip_bf16.h>

#define N_PTS 8192
#define N_SAMP 2048
#define KNN_K 16
#define NBATCH 4
#define BN_M (NBATCH * N_SAMP * KNN_K)  // 131072

typedef float f32x2 __attribute__((ext_vector_type(2)));

// u32 max/min with DPP-shuffled partner (VALU pipe only). bound_ctrl=false +
// old=src: lanes with invalid sources keep their own value (idempotent op).
// NOTE (R5 lesson): xor1,xor2,ror4,ror8 give ALL lanes the row max, but
// bcast15/bcast31 complete the wave reduction ONLY in lanes 48..63. Any
// consumer needs readlane(...,63) to get a wave-uniform value.
template <int CTRL, int RM>
__device__ __forceinline__ unsigned umax_dpp(unsigned v) {
  unsigned o = (unsigned)__builtin_amdgcn_update_dpp((int)v, (int)v, CTRL, RM, 0xF, false);
  return (o > v) ? o : v;
}
template <int CTRL, int RM>
__device__ __forceinline__ unsigned umin_dpp(unsigned v) {
  unsigned o = (unsigned)__builtin_amdgcn_update_dpp((int)v, (int)v, CTRL, RM, 0xF, false);
  return (o < v) ? o : v;
}
// u64 max via two DPP movs + compare-select (validated in R3).
template <int CTRL, int RM>
__device__ __forceinline__ unsigned long long kmax_dpp(unsigned long long k) {
  int lo = (int)(unsigned)k, hi = (int)(unsigned)(k >> 32);
  int lo2 = __builtin_amdgcn_update_dpp(lo, lo, CTRL, RM, 0xF, false);
  int hi2 = __builtin_amdgcn_update_dpp(hi, hi, CTRL, RM, 0xF, false);
  unsigned long long o = ((unsigned long long)(unsigned)hi2 << 32) | (unsigned)lo2;
  return (o > k) ? o : k;
}

// ---------------------------------------------------------------- FPS
// One block per batch, 512 threads, 16 pts/thread in registers (8x f32x2).
// Per iter (ONE barrier, no LDS atomics):
//   distances + pk-min update (vector ops so LLVM emits v_pk_*; contract off
//   => bit-exact vs reference)
//   -> wave u32 value-max via 6 DPP levels -> readlane 63 => g_wave (SGPR)
//   -> equality scan vs g_wave (cndmask chain) for lowest local matching idx
//   -> wave u32 idx-min via 6 DPP levels -> readlane 63 => c_wave (SGPR)
//      (ties -> lowest global index = jnp.argmax first-occurrence)
//   -> lane0 packs (g_wave<<32)|(0x3FFF-c_wave) into redbuf[parity][wid]
//   -> barrier -> 1 ds_read_b64 + 3 u64 DPP-max levels (period-8 replicated
//      => all-lane uniform) -> every thread holds global winner (cur).
// Double-buffered redbuf makes the single barrier race-free.
__global__ __launch_bounds__(512) void fps_kernel(const float* __restrict__ xyz,
                                                  int* __restrict__ fps_idx,
                                                  float* __restrict__ new_xyz) {
#pragma clang fp contract(off)
  __shared__ __align__(16) float xyzw[N_PTS * 4];
  __shared__ int samp[N_SAMP];
  __shared__ unsigned long long redbuf[2][8];
  const int b = blockIdx.x;
  const int tid = threadIdx.x;
  const int lane = tid & 63;
  const int wid = tid >> 6;
  const float* base = xyz + (size_t)b * N_PTS * 3;
  for (int i = tid; i < N_PTS * 3; i += 512) {
    float v = base[i];
    int p = i / 3, c = i - p * 3;
    xyzw[p * 4 + c] = v;
  }
  for (int i = tid; i < N_PTS; i += 512) xyzw[i * 4 + 3] = 0.f;
  if (tid == 0) samp[0] = 0;
  __syncthreads();

  // point k (k=0..15) of this thread is index k*512+tid; pair j holds k=2j,2j+1
  f32x2 px[8], py[8], pz[8], dmin[8];
#pragma unroll
  for (int j = 0; j < 8; ++j) {
    int p0 = (2 * j) * 512 + tid, p1 = p0 + 512;
    const float4 a = *reinterpret_cast<const float4*>(&xyzw[p0 * 4]);
    const float4 c = *reinterpret_cast<const float4*>(&xyzw[p1 * 4]);
    px[j] = f32x2{a.x, c.x};
    py[j] = f32x2{a.y, c.y};
    pz[j] = f32x2{a.z, c.z};
    dmin[j] = f32x2{1e10f, 1e10f};
  }
  unsigned cur = 0;
  for (int it = 1; it < N_SAMP; ++it) {
    const float4 c4 = *reinterpret_cast<const float4*>(&xyzw[cur * 4]);
    f32x2 cX = {c4.x, c4.x}, cY = {c4.y, c4.y}, cZ = {c4.z, c4.z};
#pragma unroll
    for (int j = 0; j < 8; ++j) {
      // match reference: sub, square, left-assoc add; contraction OFF
      f32x2 dx = px[j] - cX;
      f32x2 dy = py[j] - cY;
      f32x2 dz = pz[j] - cZ;
      f32x2 s01 = dx * dx + dy * dy;
      f32x2 d = s01 + dz * dz;
      dmin[j] = __builtin_elementwise_min(dmin[j], d);
    }
    // thread-local max (vector tree; index recovered by scan below)
    f32x2 m0 = __builtin_elementwise_max(dmin[0], dmin[1]);
    f32x2 m1 = __builtin_elementwise_max(dmin[2], dmin[3]);
    f32x2 m2 = __builtin_elementwise_max(dmin[4], dmin[5]);
    f32x2 m3 = __builtin_elementwise_max(dmin[6], dmin[7]);
    f32x2 n0 = __builtin_elementwise_max(m0, m1);
    f32x2 n1 = __builtin_elementwise_max(m2, m3);
    f32x2 nn = __builtin_elementwise_max(n0, n1);
    const unsigned bd = __float_as_uint(fmaxf(nn.x, nn.y));
    // wave value max -> lane 63, then SGPR broadcast (wave-uniform)
    unsigned r = bd;
    r = umax_dpp<0xB1, 0xF>(r);
    r = umax_dpp<0x4E, 0xF>(r);
    r = umax_dpp<0x124, 0xF>(r);
    r = umax_dpp<0x128, 0xF>(r);
    r = umax_dpp<0x142, 0xA>(r);
    r = umax_dpp<0x143, 0xC>(r);
    const unsigned g_wave = (unsigned)__builtin_amdgcn_readlane((int)r, 63);
    // lowest local point idx with dmin == wave max (cndmask chain, no branch)
    unsigned cand = 0xFFFFFFFFu;
#pragma unroll
    for (int j = 7; j >= 0; --j) {  // descending => lowest idx wins
      cand = (__float_as_uint(dmin[j].y) == g_wave) ? (unsigned)((2 * j + 1) * 512 + tid) : cand;
      cand = (__float_as_uint(dmin[j].x) == g_wave) ? (unsigned)((2 * j) * 512 + tid) : cand;
    }
    // wave idx-min over matching lanes -> lane 63 -> SGPR
    cand = umin_dpp<0xB1, 0xF>(cand);
    cand = umin_dpp<0x4E, 0xF>(cand);
    cand = umin_dpp<0x124, 0xF>(cand);
    cand = umin_dpp<0x128, 0xF>(cand);
    cand = umin_dpp<0x142, 0xA>(cand);
    cand = umin_dpp<0x143, 0xC>(cand);
    const unsigned c_wave = (unsigned)__builtin_amdgcn_readlane((int)cand, 63);
    if (lane == 0)
      redbuf[it & 1][wid] = ((unsigned long long)g_wave << 32) | (unsigned)(0x3FFF - c_wave);
    __syncthreads();
    // combine 8 wave keys: period-8 replicated; xor1+xor2+ror4 => all lanes
    // hold the max over all 8 distinct values (uniform)
    unsigned long long k2 = redbuf[it & 1][lane & 7];
    k2 = kmax_dpp<0xB1, 0xF>(k2);
    k2 = kmax_dpp<0x4E, 0xF>(k2);
    k2 = kmax_dpp<0x124, 0xF>(k2);
    cur = 0x3FFFu - (unsigned)(k2 & 0xFFFFFFFFu);
    if (tid == 0) samp[it] = (int)cur;
  }
  __syncthreads();
  for (int s = tid; s < N_SAMP; s += 512) {
    int idx = samp[s];
    fps_idx[b * N_SAMP + s] = idx;
    size_t o = ((size_t)b * N_SAMP + s) * 3;
    new_xyz[o] = xyzw[idx * 4 + 0];
    new_xyz[o + 1] = xyzw[idx * 4 + 1];
    new_xyz[o + 2] = xyzw[idx * 4 + 2];
  }
}

// ---------------------------------------------------------------- kNN
// One wave per query. Per-lane sorted top-16 (packed u64), 16-round
// wave-min merge. d = (qn+pn) - 2*dot, dot as fma chain (Eigen-gemm style).
__global__ __launch_bounds__(256) void knn_kernel(const float* __restrict__ xyz,
                                                  const float* __restrict__ new_xyz,
                                                  int* __restrict__ knn_idx) {
  const int wid = threadIdx.x >> 6, lane = threadIdx.x & 63;
  const int q = blockIdx.x * 4 + wid;
  const int b = q >> 11;
  const float* qp = new_xyz + (size_t)q * 3;
  float q0 = qp[0], q1 = qp[1], q2 = qp[2];
  float qn = __fadd_rn(__fadd_rn(__fmul_rn(q0, q0), __fmul_rn(q1, q1)), __fmul_rn(q2, q2));
  const float* pb = xyz + (size_t)b * N_PTS * 3;
  unsigned long long arr[16];
#pragma unroll
  for (int i = 0; i < 16; ++i) arr[i] = ~0ull;
  for (int p = lane; p < N_PTS; p += 64) {
    float p0 = pb[p * 3 + 0], p1 = pb[p * 3 + 1], p2 = pb[p * 3 + 2];
    float pn = __fadd_rn(__fadd_rn(__fmul_rn(p0, p0), __fmul_rn(p1, p1)), __fmul_rn(p2, p2));
    float dt = fmaf(q2, p2, fmaf(q1, p1, __fmul_rn(q0, p0)));
    float d = __fsub_rn(__fadd_rn(qn, pn), __fmul_rn(2.0f, dt));
    unsigned ub = __float_as_uint(d);
    ub ^= (unsigned)((int)ub >> 31) | 0x80000000u;  // order-preserving map (handles d<0)
    unsigned long long key = ((unsigned long long)ub << 32) | (unsigned)p;
    if (key < arr[15]) {
      unsigned long long curk = key;
#pragma unroll
      for (int j = 0; j < 16; ++j) {
        unsigned long long lo = (curk < arr[j]) ? curk : arr[j];
        unsigned long long hi = (curk < arr[j]) ? arr[j] : curk;
        arr[j] = lo; curk = hi;
      }
    }
  }
  for (int r = 0; r < KNN_K; ++r) {
    unsigned long long m = arr[0];
#pragma unroll
    for (int o = 32; o > 0; o >>= 1) {
      unsigned long long other = __shfl_xor(m, o, 64);
      m = (other < m) ? other : m;
    }
    if (arr[0] == m) {  // unique winner (idx in low bits)
#pragma unroll
      for (int j = 0; j < 15; ++j) arr[j] = arr[j + 1];
      arr[15] = ~0ull;
    }
    if (lane == r) knn_idx[(size_t)q * KNN_K + r] = (int)(m & 0xFFFFFFFFu);
  }
}

// ---------------------------------------------------------------- MLP passes
// PASS 0: mm1 -> stats1.  PASS 1: mm1->BN1->relu->mm2 -> stats2.
// PASS 2: full chain -> BN2 -> relu -> max over K -> out.
// Block = one (b,s): 16 rows (K) x 128 ch; thread (k, cg) owns 8 channels.
template <int PASS>
__global__ __launch_bounds__(256) void mlp_kernel(
    const float* __restrict__ xyz, const float* __restrict__ feat,
    const float* __restrict__ W1, const float* __restrict__ g1v, const float* __restrict__ b1v,
    const float* __restrict__ W2, const float* __restrict__ g2v, const float* __restrict__ b2v,
    const float* __restrict__ new_xyz, const int* __restrict__ knn_idx,
    float* __restrict__ stats1, float* __restrict__ stats2,
    float* __restrict__ out_feat) {
  constexpr int BUFA = (PASS == 0) ? (67 * 128) : (128 * 128);
  constexpr int ZR = (PASS == 0) ? 1 : 16;
  __shared__ __align__(16) float bufA[BUFA];     // W1, then (PASS>=1) W2
  __shared__ float xrow[16][68];
  __shared__ float zS[ZR][132];
  __shared__ float spart[4][16][16];
  __shared__ int nidx[16];
  __shared__ float qv[3];
  const int tid = threadIdx.x;
  const int bs = blockIdx.x;
  const int b = bs >> 11;
  const int lane = tid & 63, w = tid >> 6;
  const int k = tid >> 4, cg = tid & 15;
  const float inv_m = 1.0f / (float)BN_M;

  if (tid < 16) nidx[tid] = knn_idx[(size_t)bs * KNN_K + tid];
  if (tid >= 32 && tid < 35) qv[tid - 32] = new_xyz[(size_t)bs * 3 + (tid - 32)];
  for (int i = tid; i < 67 * 128; i += 256) bufA[i] = W1[i];
  __syncthreads();
  for (int i = tid; i < 16 * 64; i += 256) {
    int kk = i >> 6, c = i & 63;
    xrow[kk][c] = feat[((size_t)b * N_PTS + nidx[kk]) * 64 + c];
  }
  if (tid < 48) {
    int kk = tid / 3, c = tid - kk * 3;
    xrow[kk][64 + c] = __fsub_rn(xyz[((size_t)b * N_PTS + nidx[kk]) * 3 + c], qv[c]);
  }
  __syncthreads();

  float acc[8];
#pragma unroll
  for (int i = 0; i < 8; ++i) acc[i] = 0.f;
  for (int j = 0; j < 67; ++j) {
    float xv = xrow[k][j];
    const float4* wp = reinterpret_cast<const float4*>(&bufA[j * 128 + cg * 8]);
    float4 wa = wp[0], wb = wp[1];
    acc[0] = fmaf(xv, wa.x, acc[0]); acc[1] = fmaf(xv, wa.y, acc[1]);
    acc[2] = fmaf(xv, wa.z, acc[2]); acc[3] = fmaf(xv, wa.w, acc[3]);
    acc[4] = fmaf(xv, wb.x, acc[4]); acc[5] = fmaf(xv, wb.y, acc[5]);
    acc[6] = fmaf(xv, wb.z, acc[6]); acc[7] = fmaf(xv, wb.w, acc[7]);
  }

  if constexpr (PASS == 0) {
    float sq[8];
#pragma unroll
    for (int i = 0; i < 8; ++i) sq[i] = acc[i] * acc[i];
#pragma unroll
    for (int i = 0; i < 8; ++i) {
      acc[i] += __shfl_xor(acc[i], 16, 64); sq[i] += __shfl_xor(sq[i], 16, 64);
      acc[i] += __shfl_xor(acc[i], 32, 64); sq[i] += __shfl_xor(sq[i], 32, 64);
    }
    if (lane < 16) {
#pragma unroll
      for (int i = 0; i < 8; ++i) { spart[w][cg][i] = acc[i]; spart[w][cg][8 + i] = sq[i]; }
    }
    __syncthreads();
    {
      int ch = tid & 127, half = tid >> 7;
      float v = 0.f;
#pragma unroll
      for (int ww = 0; ww < 4; ++ww) v += spart[ww][ch >> 3][half * 8 + (ch & 7)];
      atomicAdd(&stats1[half * 128 + ch], v);
    }
    return;
  } else {
    // BN1 + relu -> zS
#pragma unroll
    for (int i = 0; i < 8; ++i) {
      int ch = cg * 8 + i;
      float mean = stats1[ch] * inv_m;
      float var = stats1[128 + ch] * inv_m - mean * mean;
      float rs = rsqrtf(var + 1e-5f);
      float zz = (acc[i] - mean) * rs * g1v[ch] + b1v[ch];
      zS[k][ch] = fmaxf(zz, 0.f);
    }
    __syncthreads();
    for (int i = tid; i < 128 * 128; i += 256) bufA[i] = W2[i];
    __syncthreads();
    float u[8];
#pragma unroll
    for (int i = 0; i < 8; ++i) u[i] = 0.f;
    for (int j = 0; j < 128; ++j) {
      float zv = zS[k][j];
      const float4* wp = reinterpret_cast<const float4*>(&bufA[j * 128 + cg * 8]);
      float4 wa = wp[0], wb = wp[1];
      u[0] = fmaf(zv, wa.x, u[0]); u[1] = fmaf(zv, wa.y, u[1]);
      u[2] = fmaf(zv, wa.z, u[2]); u[3] = fmaf(zv, wa.w, u[3]);
      u[4] = fmaf(zv, wb.x, u[4]); u[5] = fmaf(zv, wb.y, u[5]);
      u[6] = fmaf(zv, wb.z, u[6]); u[7] = fmaf(zv, wb.w, u[7]);
    }

    if constexpr (PASS == 1) {
      float sq[8];
#pragma unroll
      for (int i = 0; i < 8; ++i) sq[i] = u[i] * u[i];
#pragma unroll
      for (int i = 0; i < 8; ++i) {
        u[i] += __shfl_xor(u[i], 16, 64); sq[i] += __shfl_xor(sq[i], 16, 64);
        u[i] += __shfl_xor(u[i], 32, 64); sq[i] += __shfl_xor(sq[i], 32, 64);
      }
      if (lane < 16) {
#pragma unroll
        for (int i = 0; i < 8; ++i) { spart[w][cg][i] = u[i]; spart[w][cg][8 + i] = sq[i]; }
      }
      __syncthreads();
      {
        int ch = tid & 127, half = tid >> 7;
        float v = 0.f;
#pragma unroll
        for (int ww = 0; ww < 4; ++ww) v += spart[ww][ch >> 3][half * 8 + (ch & 7)];
        atomicAdd(&stats2[half * 128 + ch], v);
      }
      return;
    } else {
      // BN2 + relu + max over K
      float v8[8];
#pragma unroll
      for (int i = 0; i < 8; ++i) {
        int ch = cg * 8 + i;
        float mean = stats2[ch] * inv_m;
        float var = stats2[128 + ch] * inv_m - mean * mean;
        float rs = rsqrtf(var + 1e-5f);
        float vv = (u[i] - mean) * rs * g2v[ch] + b2v[ch];
        v8[i] = fmaxf(vv, 0.f);
      }
#pragma unroll
      for (int i = 0; i < 8; ++i) {
        v8[i] = fmaxf(v8[i], __shfl_xor(v8[i], 16, 64));
        v8[i] = fmaxf(v8[i], __shfl_xor(v8[i], 32, 64));
      }
      if (lane < 16) {
#pragma unroll
        for (int i = 0; i < 8; ++i) spart[w][cg][i] = v8[i];
      }
      __syncthreads();
      if (tid < 128) {
        int ch = tid;
        float m = spart[0][ch >> 3][ch & 7];
#pragma unroll
        for (int ww = 1; ww < 4; ++ww) m = fmaxf(m, spart[ww][ch >> 3][ch & 7]);
        out_feat[(size_t)bs * 128 + ch] = m;
      }
    }
  }
}

extern "C" void kernel_launch(void* const* d_in, const int* in_sizes, int n_in,
                              void* d_out, int out_size, void* d_ws, size_t ws_size,
                              hipStream_t stream) {
  const float* xyz  = (const float*)d_in[0];
  const float* feat = (const float*)d_in[1];
  const float* W1   = (const float*)d_in[2];
  const float* g1   = (const float*)d_in[3];
  const float* b1   = (const float*)d_in[4];
  const float* W2   = (const float*)d_in[5];
  const float* g2   = (const float*)d_in[6];
  const float* b2   = (const float*)d_in[7];
  float* out = (float*)d_out;
  float* new_xyz = out;                              // [4,2048,3]
  float* out_feat = out + NBATCH * N_SAMP * 3;       // [4,2048,128]

  int* fps_i = (int*)d_ws;                           // [4,2048]
  int* knn_i = fps_i + NBATCH * N_SAMP;              // [4,2048,16]
  float* stats1 = (float*)(knn_i + NBATCH * N_SAMP * KNN_K);  // [256]
  float* stats2 = stats1 + 256;                      // [256]

  hipMemsetAsync(stats1, 0, 512 * sizeof(float), stream);
  hipLaunchKernelGGL(fps_kernel, dim3(NBATCH), dim3(512), 0, stream, xyz, fps_i, new_xyz);
  hipLaunchKernelGGL(knn_kernel, dim3((NBATCH * N_SAMP) / 4), dim3(256), 0, stream,
                     xyz, new_xyz, knn_i);
  hipLaunchKernelGGL((mlp_kernel<0>), dim3(NBATCH * N_SAMP), dim3(256), 0, stream,
                     xyz, feat, W1, g1, b1, W2, g2, b2, new_xyz, knn_i, stats1, stats2, out_feat);
  hipLaunchKernelGGL((mlp_kernel<1>), dim3(NBATCH * N_SAMP), dim3(256), 0, stream,
                     xyz, feat, W1, g1, b1, W2, g2, b2, new_xyz, knn_i, stats1, stats2, out_feat);
  hipLaunchKernelGGL((mlp_kernel<2>), dim3(NBATCH * N_SAMP), dim3(256), 0, stream,
                     xyz, feat, W1, g1, b1, W2, g2, b2, new_xyz, knn_i, stats1, stats2, out_feat);
}

// Round 7
// 2268.804 us; speedup vs baseline: 1.3589x; 1.3589x over previous
//
#include <hip/hip_runtime.h>
#include <hip/hip_bf16.h>

#define N_PTS 8192
#define N_SAMP 2048
#define KNN_K 16
#define NBATCH 4
#define BN_M (NBATCH * N_SAMP * KNN_K)  // 131072
#define NROWS (N_SAMP * NBATCH * KNN_K) // 131072 rows of the im2col matrix

typedef float f32x2 __attribute__((ext_vector_type(2)));

// u32 max/min with DPP-shuffled partner (VALU pipe only). bound_ctrl=false +
// old=src: lanes with invalid sources keep their own value (idempotent op).
// NOTE (R5 lesson): bcast15/bcast31 complete the wave reduction ONLY in lanes
// 48..63; consumers need readlane(...,63) for a wave-uniform value.
template <int CTRL, int RM>
__device__ __forceinline__ unsigned umax_dpp(unsigned v) {
  unsigned o = (unsigned)__builtin_amdgcn_update_dpp((int)v, (int)v, CTRL, RM, 0xF, false);
  return (o > v) ? o : v;
}
template <int CTRL, int RM>
__device__ __forceinline__ unsigned umin_dpp(unsigned v) {
  unsigned o = (unsigned)__builtin_amdgcn_update_dpp((int)v, (int)v, CTRL, RM, 0xF, false);
  return (o < v) ? o : v;
}
template <int CTRL, int RM>
__device__ __forceinline__ unsigned long long kmax_dpp(unsigned long long k) {
  int lo = (int)(unsigned)k, hi = (int)(unsigned)(k >> 32);
  int lo2 = __builtin_amdgcn_update_dpp(lo, lo, CTRL, RM, 0xF, false);
  int hi2 = __builtin_amdgcn_update_dpp(hi, hi, CTRL, RM, 0xF, false);
  unsigned long long o = ((unsigned long long)(unsigned)hi2 << 32) | (unsigned)lo2;
  return (o > k) ? o : k;
}

// ---------------------------------------------------------------- FPS (R6, validated)
__global__ __launch_bounds__(512) void fps_kernel(const float* __restrict__ xyz,
                                                  int* __restrict__ fps_idx,
                                                  float* __restrict__ new_xyz) {
#pragma clang fp contract(off)
  __shared__ __align__(16) float xyzw[N_PTS * 4];
  __shared__ int samp[N_SAMP];
  __shared__ unsigned long long redbuf[2][8];
  const int b = blockIdx.x;
  const int tid = threadIdx.x;
  const int lane = tid & 63;
  const int wid = tid >> 6;
  const float* base = xyz + (size_t)b * N_PTS * 3;
  for (int i = tid; i < N_PTS * 3; i += 512) {
    float v = base[i];
    int p = i / 3, c = i - p * 3;
    xyzw[p * 4 + c] = v;
  }
  for (int i = tid; i < N_PTS; i += 512) xyzw[i * 4 + 3] = 0.f;
  if (tid == 0) samp[0] = 0;
  __syncthreads();

  f32x2 px[8], py[8], pz[8], dmin[8];
#pragma unroll
  for (int j = 0; j < 8; ++j) {
    int p0 = (2 * j) * 512 + tid, p1 = p0 + 512;
    const float4 a = *reinterpret_cast<const float4*>(&xyzw[p0 * 4]);
    const float4 c = *reinterpret_cast<const float4*>(&xyzw[p1 * 4]);
    px[j] = f32x2{a.x, c.x};
    py[j] = f32x2{a.y, c.y};
    pz[j] = f32x2{a.z, c.z};
    dmin[j] = f32x2{1e10f, 1e10f};
  }
  unsigned cur = 0;
  for (int it = 1; it < N_SAMP; ++it) {
    const float4 c4 = *reinterpret_cast<const float4*>(&xyzw[cur * 4]);
    f32x2 cX = {c4.x, c4.x}, cY = {c4.y, c4.y}, cZ = {c4.z, c4.z};
#pragma unroll
    for (int j = 0; j < 8; ++j) {
      f32x2 dx = px[j] - cX;
      f32x2 dy = py[j] - cY;
      f32x2 dz = pz[j] - cZ;
      f32x2 s01 = dx * dx + dy * dy;
      f32x2 d = s01 + dz * dz;
      dmin[j] = __builtin_elementwise_min(dmin[j], d);
    }
    f32x2 m0 = __builtin_elementwise_max(dmin[0], dmin[1]);
    f32x2 m1 = __builtin_elementwise_max(dmin[2], dmin[3]);
    f32x2 m2 = __builtin_elementwise_max(dmin[4], dmin[5]);
    f32x2 m3 = __builtin_elementwise_max(dmin[6], dmin[7]);
    f32x2 n0 = __builtin_elementwise_max(m0, m1);
    f32x2 n1 = __builtin_elementwise_max(m2, m3);
    f32x2 nn = __builtin_elementwise_max(n0, n1);
    const unsigned bd = __float_as_uint(fmaxf(nn.x, nn.y));
    unsigned r = bd;
    r = umax_dpp<0xB1, 0xF>(r);
    r = umax_dpp<0x4E, 0xF>(r);
    r = umax_dpp<0x124, 0xF>(r);
    r = umax_dpp<0x128, 0xF>(r);
    r = umax_dpp<0x142, 0xA>(r);
    r = umax_dpp<0x143, 0xC>(r);
    const unsigned g_wave = (unsigned)__builtin_amdgcn_readlane((int)r, 63);
    unsigned cand = 0xFFFFFFFFu;
#pragma unroll
    for (int j = 7; j >= 0; --j) {
      cand = (__float_as_uint(dmin[j].y) == g_wave) ? (unsigned)((2 * j + 1) * 512 + tid) : cand;
      cand = (__float_as_uint(dmin[j].x) == g_wave) ? (unsigned)((2 * j) * 512 + tid) : cand;
    }
    cand = umin_dpp<0xB1, 0xF>(cand);
    cand = umin_dpp<0x4E, 0xF>(cand);
    cand = umin_dpp<0x124, 0xF>(cand);
    cand = umin_dpp<0x128, 0xF>(cand);
    cand = umin_dpp<0x142, 0xA>(cand);
    cand = umin_dpp<0x143, 0xC>(cand);
    const unsigned c_wave = (unsigned)__builtin_amdgcn_readlane((int)cand, 63);
    if (lane == 0)
      redbuf[it & 1][wid] = ((unsigned long long)g_wave << 32) | (unsigned)(0x3FFF - c_wave);
    __syncthreads();
    unsigned long long k2 = redbuf[it & 1][lane & 7];
    k2 = kmax_dpp<0xB1, 0xF>(k2);
    k2 = kmax_dpp<0x4E, 0xF>(k2);
    k2 = kmax_dpp<0x124, 0xF>(k2);
    cur = 0x3FFFu - (unsigned)(k2 & 0xFFFFFFFFu);
    if (tid == 0) samp[it] = (int)cur;
  }
  __syncthreads();
  for (int s = tid; s < N_SAMP; s += 512) {
    int idx = samp[s];
    fps_idx[b * N_SAMP + s] = idx;
    size_t o = ((size_t)b * N_SAMP + s) * 3;
    new_xyz[o] = xyzw[idx * 4 + 0];
    new_xyz[o + 1] = xyzw[idx * 4 + 1];
    new_xyz[o + 2] = xyzw[idx * 4 + 2];
  }
}

// ---------------------------------------------------------------- kNN (unchanged)
__global__ __launch_bounds__(256) void knn_kernel(const float* __restrict__ xyz,
                                                  const float* __restrict__ new_xyz,
                                                  int* __restrict__ knn_idx) {
  const int wid = threadIdx.x >> 6, lane = threadIdx.x & 63;
  const int q = blockIdx.x * 4 + wid;
  const int b = q >> 11;
  const float* qp = new_xyz + (size_t)q * 3;
  float q0 = qp[0], q1 = qp[1], q2 = qp[2];
  float qn = __fadd_rn(__fadd_rn(__fmul_rn(q0, q0), __fmul_rn(q1, q1)), __fmul_rn(q2, q2));
  const float* pb = xyz + (size_t)b * N_PTS * 3;
  unsigned long long arr[16];
#pragma unroll
  for (int i = 0; i < 16; ++i) arr[i] = ~0ull;
  for (int p = lane; p < N_PTS; p += 64) {
    float p0 = pb[p * 3 + 0], p1 = pb[p * 3 + 1], p2 = pb[p * 3 + 2];
    float pn = __fadd_rn(__fadd_rn(__fmul_rn(p0, p0), __fmul_rn(p1, p1)), __fmul_rn(p2, p2));
    float dt = fmaf(q2, p2, fmaf(q1, p1, __fmul_rn(q0, p0)));
    float d = __fsub_rn(__fadd_rn(qn, pn), __fmul_rn(2.0f, dt));
    unsigned ub = __float_as_uint(d);
    ub ^= (unsigned)((int)ub >> 31) | 0x80000000u;
    unsigned long long key = ((unsigned long long)ub << 32) | (unsigned)p;
    if (key < arr[15]) {
      unsigned long long curk = key;
#pragma unroll
      for (int j = 0; j < 16; ++j) {
        unsigned long long lo = (curk < arr[j]) ? curk : arr[j];
        unsigned long long hi = (curk < arr[j]) ? arr[j] : curk;
        arr[j] = lo; curk = hi;
      }
    }
  }
  for (int r = 0; r < KNN_K; ++r) {
    unsigned long long m = arr[0];
#pragma unroll
    for (int o = 32; o > 0; o >>= 1) {
      unsigned long long other = __shfl_xor(m, o, 64);
      m = (other < m) ? other : m;
    }
    if (arr[0] == m) {
#pragma unroll
      for (int j = 0; j < 15; ++j) arr[j] = arr[j + 1];
      arr[15] = ~0ull;
    }
    if (lane == r) knn_idx[(size_t)q * KNN_K + r] = (int)(m & 0xFFFFFFFFu);
  }
}

// ---------------------------------------------------------------- NEW MLP (ws path)
// P0: gather rows -> A^T in LDS -> y1 = A@W1 (128x128 tile, 8x8/thread) + stats1
__global__ __launch_bounds__(256) void gemm1_kernel(
    const float* __restrict__ xyz, const float* __restrict__ feat,
    const float* __restrict__ W1, const float* __restrict__ new_xyz,
    const int* __restrict__ knn_i, float* __restrict__ y1, float* __restrict__ stats1) {
  __shared__ __align__(16) float At[67 * 128];   // A^T[k][row]
  __shared__ __align__(16) float Wq[17 * 128];   // W1 k-quarter
  __shared__ float part[4 * 256];
  __shared__ int nb[128];
  const int t = threadIdx.x, blk = blockIdx.x;
  const int row0 = blk * 128;
  if (t < 128) nb[t] = knn_i[row0 + t];
  __syncthreads();
  {  // stage A^T (gathered feat + centered xyz)
    const int r = t >> 1, q = t & 1;
    const int rg = row0 + r, bs = rg >> 4, b = bs >> 11;
    const float* fr = feat + ((size_t)b * N_PTS + nb[r]) * 64 + q * 32;
#pragma unroll
    for (int i = 0; i < 8; ++i) {
      float4 v = *reinterpret_cast<const float4*>(fr + 4 * i);
      int c = q * 32 + 4 * i;
      At[(c + 0) * 128 + r] = v.x; At[(c + 1) * 128 + r] = v.y;
      At[(c + 2) * 128 + r] = v.z; At[(c + 3) * 128 + r] = v.w;
    }
    if (q == 0) {
      const float* pr = xyz + ((size_t)b * N_PTS + nb[r]) * 3;
      const float* qr = new_xyz + (size_t)bs * 3;
      At[64 * 128 + r] = pr[0] - qr[0];
      At[65 * 128 + r] = pr[1] - qr[1];
      At[66 * 128 + r] = pr[2] - qr[2];
    }
  }
  float acc[8][8];
#pragma unroll
  for (int i = 0; i < 8; ++i)
#pragma unroll
    for (int j = 0; j < 8; ++j) acc[i][j] = 0.f;
  const int ry = t >> 4, cx = t & 15;
  for (int kq = 0; kq < 4; ++kq) {
    const int kbase = kq * 17;
    const int nk = (67 - kbase) < 17 ? (67 - kbase) : 17;
    __syncthreads();
    for (int i = t; i < nk * 32; i += 256)
      reinterpret_cast<float4*>(Wq)[i] =
          reinterpret_cast<const float4*>(W1 + (size_t)kbase * 128)[i];
    __syncthreads();
    for (int kk = 0; kk < nk; ++kk) {
      const float4 a0 = *reinterpret_cast<const float4*>(&At[(kbase + kk) * 128 + ry * 8]);
      const float4 a1 = *reinterpret_cast<const float4*>(&At[(kbase + kk) * 128 + ry * 8 + 4]);
      const float4 w0 = *reinterpret_cast<const float4*>(&Wq[kk * 128 + cx * 8]);
      const float4 w1 = *reinterpret_cast<const float4*>(&Wq[kk * 128 + cx * 8 + 4]);
      const float a[8] = {a0.x, a0.y, a0.z, a0.w, a1.x, a1.y, a1.z, a1.w};
      const float w[8] = {w0.x, w0.y, w0.z, w0.w, w1.x, w1.y, w1.z, w1.w};
#pragma unroll
      for (int i = 0; i < 8; ++i)
#pragma unroll
        for (int j = 0; j < 8; ++j) acc[i][j] = fmaf(a[i], w[j], acc[i][j]);
    }
  }
  // y1 store
#pragma unroll
  for (int i = 0; i < 8; ++i) {
    float4 v0 = {acc[i][0], acc[i][1], acc[i][2], acc[i][3]};
    float4 v1 = {acc[i][4], acc[i][5], acc[i][6], acc[i][7]};
    float* dst = y1 + ((size_t)row0 + ry * 8 + i) * 128 + cx * 8;
    *reinterpret_cast<float4*>(dst) = v0;
    *reinterpret_cast<float4*>(dst + 4) = v1;
  }
  // stats
  float s8[8], q8[8];
#pragma unroll
  for (int j = 0; j < 8; ++j) {
    s8[j] = 0.f; q8[j] = 0.f;
#pragma unroll
    for (int i = 0; i < 8; ++i) { s8[j] += acc[i][j]; q8[j] += acc[i][j] * acc[i][j]; }
  }
#pragma unroll
  for (int j = 0; j < 8; ++j) {
    s8[j] += __shfl_xor(s8[j], 16, 64); q8[j] += __shfl_xor(q8[j], 16, 64);
    s8[j] += __shfl_xor(s8[j], 32, 64); q8[j] += __shfl_xor(q8[j], 32, 64);
  }
  const int w = t >> 6, lane = t & 63;
  if (lane < 16) {
#pragma unroll
    for (int j = 0; j < 8; ++j) {
      part[w * 256 + lane * 8 + j] = s8[j];
      part[w * 256 + 128 + lane * 8 + j] = q8[j];
    }
  }
  __syncthreads();
  {
    int ch = t & 127, which = t >> 7;
    float v = part[0 * 256 + which * 128 + ch] + part[1 * 256 + which * 128 + ch] +
              part[2 * 256 + which * 128 + ch] + part[3 * 256 + which * 128 + ch];
    atomicAdd(&stats1[which * 128 + ch], v);
  }
}

// P1: z1 = relu(BN1(y1)) staged transposed -> y2 = z1@W2 + stats2
__global__ __launch_bounds__(256) void gemm2_kernel(
    const float* __restrict__ y1, const float* __restrict__ W2,
    const float* __restrict__ stats1, const float* __restrict__ g1v,
    const float* __restrict__ b1v, float* __restrict__ y2, float* __restrict__ stats2) {
  __shared__ __align__(16) float Ah[64 * 128];   // z1^T half [k_loc][row]
  __shared__ __align__(16) float Wq[32 * 128];   // W2 k-quarter
  __shared__ float part[4 * 256];
  __shared__ float s1[128], h1[128];
  const int t = threadIdx.x, blk = blockIdx.x;
  const int row0 = blk * 128;
  const float inv_m = 1.0f / (float)BN_M;
  if (t < 128) {
    float m = stats1[t] * inv_m;
    float var = stats1[128 + t] * inv_m - m * m;
    float rs = rsqrtf(var + 1e-5f);
    float sc = rs * g1v[t];
    s1[t] = sc;
    h1[t] = b1v[t] - m * sc;
  }
  float acc[8][8];
#pragma unroll
  for (int i = 0; i < 8; ++i)
#pragma unroll
    for (int j = 0; j < 8; ++j) acc[i][j] = 0.f;
  const int ry = t >> 4, cx = t & 15;
  for (int kh = 0; kh < 2; ++kh) {
    __syncthreads();  // prior Ah reads done; s1/h1 visible on first pass
    {
      const int r = t >> 1, q = t & 1;
      const float* src = y1 + ((size_t)row0 + r) * 128 + kh * 64 + q * 32;
#pragma unroll
      for (int i = 0; i < 8; ++i) {
        float4 v = *reinterpret_cast<const float4*>(src + 4 * i);
        int c = kh * 64 + q * 32 + 4 * i;
        int cl = c - kh * 64;
        Ah[(cl + 0) * 128 + r] = fmaxf(fmaf(v.x, s1[c + 0], h1[c + 0]), 0.f);
        Ah[(cl + 1) * 128 + r] = fmaxf(fmaf(v.y, s1[c + 1], h1[c + 1]), 0.f);
        Ah[(cl + 2) * 128 + r] = fmaxf(fmaf(v.z, s1[c + 2], h1[c + 2]), 0.f);
        Ah[(cl + 3) * 128 + r] = fmaxf(fmaf(v.w, s1[c + 3], h1[c + 3]), 0.f);
      }
    }
    for (int kq = 0; kq < 2; ++kq) {
      __syncthreads();  // Ah visible / prior Wq reads done
      const int kbase = kh * 64 + kq * 32;
      for (int i = t; i < 32 * 32; i += 256)
        reinterpret_cast<float4*>(Wq)[i] =
            reinterpret_cast<const float4*>(W2 + (size_t)kbase * 128)[i];
      __syncthreads();
      for (int kk = 0; kk < 32; ++kk) {
        const int kl = kq * 32 + kk;
        const float4 a0 = *reinterpret_cast<const float4*>(&Ah[kl * 128 + ry * 8]);
        const float4 a1 = *reinterpret_cast<const float4*>(&Ah[kl * 128 + ry * 8 + 4]);
        const float4 w0 = *reinterpret_cast<const float4*>(&Wq[kk * 128 + cx * 8]);
        const float4 w1 = *reinterpret_cast<const float4*>(&Wq[kk * 128 + cx * 8 + 4]);
        const float a[8] = {a0.x, a0.y, a0.z, a0.w, a1.x, a1.y, a1.z, a1.w};
        const float w[8] = {w0.x, w0.y, w0.z, w0.w, w1.x, w1.y, w1.z, w1.w};
#pragma unroll
        for (int i = 0; i < 8; ++i)
#pragma unroll
          for (int j = 0; j < 8; ++j) acc[i][j] = fmaf(a[i], w[j], acc[i][j]);
      }
    }
  }
#pragma unroll
  for (int i = 0; i < 8; ++i) {
    float4 v0 = {acc[i][0], acc[i][1], acc[i][2], acc[i][3]};
    float4 v1 = {acc[i][4], acc[i][5], acc[i][6], acc[i][7]};
    float* dst = y2 + ((size_t)row0 + ry * 8 + i) * 128 + cx * 8;
    *reinterpret_cast<float4*>(dst) = v0;
    *reinterpret_cast<float4*>(dst + 4) = v1;
  }
  float s8[8], q8[8];
#pragma unroll
  for (int j = 0; j < 8; ++j) {
    s8[j] = 0.f; q8[j] = 0.f;
#pragma unroll
    for (int i = 0; i < 8; ++i) { s8[j] += acc[i][j]; q8[j] += acc[i][j] * acc[i][j]; }
  }
#pragma unroll
  for (int j = 0; j < 8; ++j) {
    s8[j] += __shfl_xor(s8[j], 16, 64); q8[j] += __shfl_xor(q8[j], 16, 64);
    s8[j] += __shfl_xor(s8[j], 32, 64); q8[j] += __shfl_xor(q8[j], 32, 64);
  }
  const int w = t >> 6, lane = t & 63;
  if (lane < 16) {
#pragma unroll
    for (int j = 0; j < 8; ++j) {
      part[w * 256 + lane * 8 + j] = s8[j];
      part[w * 256 + 128 + lane * 8 + j] = q8[j];
    }
  }
  __syncthreads();
  {
    int ch = t & 127, which = t >> 7;
    float v = part[0 * 256 + which * 128 + ch] + part[1 * 256 + which * 128 + ch] +
              part[2 * 256 + which * 128 + ch] + part[3 * 256 + which * 128 + ch];
    atomicAdd(&stats2[which * 128 + ch], v);
  }
}

// P2: out = max over K of relu(BN2(y2)); block = 8 samples (128 rows)
__global__ __launch_bounds__(256) void pool_kernel(
    const float* __restrict__ y2, const float* __restrict__ stats2,
    const float* __restrict__ g2v, const float* __restrict__ b2v,
    float* __restrict__ out_feat) {
  __shared__ float s2[128], h2[128];
  __shared__ float part[4 * 128];
  const int t = threadIdx.x, blk = blockIdx.x;
  const float inv_m = 1.0f / (float)BN_M;
  if (t < 128) {
    float m = stats2[t] * inv_m;
    float var = stats2[128 + t] * inv_m - m * m;
    float rs = rsqrtf(var + 1e-5f);
    float sc = rs * g2v[t];
    s2[t] = sc;
    h2[t] = b2v[t] - m * sc;
  }
  __syncthreads();
  const int c4 = (t & 31) * 4, rg = t >> 5;  // rg 0..7, 2 rows each
  const int lane = t & 63, w = t >> 6;
  for (int s = 0; s < 8; ++s) {
    const int bs = blk * 8 + s;
    float4 m4 = {-1e30f, -1e30f, -1e30f, -1e30f};
#pragma unroll
    for (int rr = 0; rr < 2; ++rr) {
      const int r = bs * 16 + rg * 2 + rr;
      float4 v = *reinterpret_cast<const float4*>(y2 + (size_t)r * 128 + c4);
      float4 z = {fmaxf(fmaf(v.x, s2[c4 + 0], h2[c4 + 0]), 0.f),
                  fmaxf(fmaf(v.y, s2[c4 + 1], h2[c4 + 1]), 0.f),
                  fmaxf(fmaf(v.z, s2[c4 + 2], h2[c4 + 2]), 0.f),
                  fmaxf(fmaf(v.w, s2[c4 + 3], h2[c4 + 3]), 0.f)};
      m4.x = fmaxf(m4.x, z.x); m4.y = fmaxf(m4.y, z.y);
      m4.z = fmaxf(m4.z, z.z); m4.w = fmaxf(m4.w, z.w);
    }
    m4.x = fmaxf(m4.x, __shfl_xor(m4.x, 32, 64));
    m4.y = fmaxf(m4.y, __shfl_xor(m4.y, 32, 64));
    m4.z = fmaxf(m4.z, __shfl_xor(m4.z, 32, 64));
    m4.w = fmaxf(m4.w, __shfl_xor(m4.w, 32, 64));
    if (lane < 32) {
      part[w * 128 + c4 + 0] = m4.x; part[w * 128 + c4 + 1] = m4.y;
      part[w * 128 + c4 + 2] = m4.z; part[w * 128 + c4 + 3] = m4.w;
    }
    __syncthreads();
    if (t < 128) {
      float mm = fmaxf(fmaxf(part[t], part[128 + t]), fmaxf(part[256 + t], part[384 + t]));
      out_feat[(size_t)bs * 128 + t] = mm;
    }
    __syncthreads();
  }
}

// ---------------------------------------------------------------- OLD MLP (fallback, validated R1-R6)
template <int PASS>
__global__ __launch_bounds__(256) void mlp_kernel(
    const float* __restrict__ xyz, const float* __restrict__ feat,
    const float* __restrict__ W1, const float* __restrict__ g1v, const float* __restrict__ b1v,
    const float* __restrict__ W2, const float* __restrict__ g2v, const float* __restrict__ b2v,
    const float* __restrict__ new_xyz, const int* __restrict__ knn_idx,
    float* __restrict__ stats1, float* __restrict__ stats2,
    float* __restrict__ out_feat) {
  constexpr int BUFA = (PASS == 0) ? (67 * 128) : (128 * 128);
  constexpr int ZR = (PASS == 0) ? 1 : 16;
  __shared__ __align__(16) float bufA[BUFA];
  __shared__ float xrow[16][68];
  __shared__ float zS[ZR][132];
  __shared__ float spart[4][16][16];
  __shared__ int nidx[16];
  __shared__ float qv[3];
  const int tid = threadIdx.x;
  const int bs = blockIdx.x;
  const int b = bs >> 11;
  const int lane = tid & 63, w = tid >> 6;
  const int k = tid >> 4, cg = tid & 15;
  const float inv_m = 1.0f / (float)BN_M;

  if (tid < 16) nidx[tid] = knn_idx[(size_t)bs * KNN_K + tid];
  if (tid >= 32 && tid < 35) qv[tid - 32] = new_xyz[(size_t)bs * 3 + (tid - 32)];
  for (int i = tid; i < 67 * 128; i += 256) bufA[i] = W1[i];
  __syncthreads();
  for (int i = tid; i < 16 * 64; i += 256) {
    int kk = i >> 6, c = i & 63;
    xrow[kk][c] = feat[((size_t)b * N_PTS + nidx[kk]) * 64 + c];
  }
  if (tid < 48) {
    int kk = tid / 3, c = tid - kk * 3;
    xrow[kk][64 + c] = __fsub_rn(xyz[((size_t)b * N_PTS + nidx[kk]) * 3 + c], qv[c]);
  }
  __syncthreads();

  float acc[8];
#pragma unroll
  for (int i = 0; i < 8; ++i) acc[i] = 0.f;
  for (int j = 0; j < 67; ++j) {
    float xv = xrow[k][j];
    const float4* wp = reinterpret_cast<const float4*>(&bufA[j * 128 + cg * 8]);
    float4 wa = wp[0], wb = wp[1];
    acc[0] = fmaf(xv, wa.x, acc[0]); acc[1] = fmaf(xv, wa.y, acc[1]);
    acc[2] = fmaf(xv, wa.z, acc[2]); acc[3] = fmaf(xv, wa.w, acc[3]);
    acc[4] = fmaf(xv, wb.x, acc[4]); acc[5] = fmaf(xv, wb.y, acc[5]);
    acc[6] = fmaf(xv, wb.z, acc[6]); acc[7] = fmaf(xv, wb.w, acc[7]);
  }

  if constexpr (PASS == 0) {
    float sq[8];
#pragma unroll
    for (int i = 0; i < 8; ++i) sq[i] = acc[i] * acc[i];
#pragma unroll
    for (int i = 0; i < 8; ++i) {
      acc[i] += __shfl_xor(acc[i], 16, 64); sq[i] += __shfl_xor(sq[i], 16, 64);
      acc[i] += __shfl_xor(acc[i], 32, 64); sq[i] += __shfl_xor(sq[i], 32, 64);
    }
    if (lane < 16) {
#pragma unroll
      for (int i = 0; i < 8; ++i) { spart[w][cg][i] = acc[i]; spart[w][cg][8 + i] = sq[i]; }
    }
    __syncthreads();
    {
      int ch = tid & 127, half = tid >> 7;
      float v = 0.f;
#pragma unroll
      for (int ww = 0; ww < 4; ++ww) v += spart[ww][ch >> 3][half * 8 + (ch & 7)];
      atomicAdd(&stats1[half * 128 + ch], v);
    }
    return;
  } else {
#pragma unroll
    for (int i = 0; i < 8; ++i) {
      int ch = cg * 8 + i;
      float mean = stats1[ch] * inv_m;
      float var = stats1[128 + ch] * inv_m - mean * mean;
      float rs = rsqrtf(var + 1e-5f);
      float zz = (acc[i] - mean) * rs * g1v[ch] + b1v[ch];
      zS[k][ch] = fmaxf(zz, 0.f);
    }
    __syncthreads();
    for (int i = tid; i < 128 * 128; i += 256) bufA[i] = W2[i];
    __syncthreads();
    float u[8];
#pragma unroll
    for (int i = 0; i < 8; ++i) u[i] = 0.f;
    for (int j = 0; j < 128; ++j) {
      float zv = zS[k][j];
      const float4* wp = reinterpret_cast<const float4*>(&bufA[j * 128 + cg * 8]);
      float4 wa = wp[0], wb = wp[1];
      u[0] = fmaf(zv, wa.x, u[0]); u[1] = fmaf(zv, wa.y, u[1]);
      u[2] = fmaf(zv, wa.z, u[2]); u[3] = fmaf(zv, wa.w, u[3]);
      u[4] = fmaf(zv, wb.x, u[4]); u[5] = fmaf(zv, wb.y, u[5]);
      u[6] = fmaf(zv, wb.z, u[6]); u[7] = fmaf(zv, wb.w, u[7]);
    }

    if constexpr (PASS == 1) {
      float sq[8];
#pragma unroll
      for (int i = 0; i < 8; ++i) sq[i] = u[i] * u[i];
#pragma unroll
      for (int i = 0; i < 8; ++i) {
        u[i] += __shfl_xor(u[i], 16, 64); sq[i] += __shfl_xor(sq[i], 16, 64);
        u[i] += __shfl_xor(u[i], 32, 64); sq[i] += __shfl_xor(sq[i], 32, 64);
      }
      if (lane < 16) {
#pragma unroll
        for (int i = 0; i < 8; ++i) { spart[w][cg][i] = u[i]; spart[w][cg][8 + i] = sq[i]; }
      }
      __syncthreads();
      {
        int ch = tid & 127, half = tid >> 7;
        float v = 0.f;
#pragma unroll
        for (int ww = 0; ww < 4; ++ww) v += spart[ww][ch >> 3][half * 8 + (ch & 7)];
        atomicAdd(&stats2[half * 128 + ch], v);
      }
      return;
    } else {
      float v8[8];
#pragma unroll
      for (int i = 0; i < 8; ++i) {
        int ch = cg * 8 + i;
        float mean = stats2[ch] * inv_m;
        float var = stats2[128 + ch] * inv_m - mean * mean;
        float rs = rsqrtf(var + 1e-5f);
        float vv = (u[i] - mean) * rs * g2v[ch] + b2v[ch];
        v8[i] = fmaxf(vv, 0.f);
      }
#pragma unroll
      for (int i = 0; i < 8; ++i) {
        v8[i] = fmaxf(v8[i], __shfl_xor(v8[i], 16, 64));
        v8[i] = fmaxf(v8[i], __shfl_xor(v8[i], 32, 64));
      }
      if (lane < 16) {
#pragma unroll
        for (int i = 0; i < 8; ++i) spart[w][cg][i] = v8[i];
      }
      __syncthreads();
      if (tid < 128) {
        int ch = tid;
        float m = spart[0][ch >> 3][ch & 7];
#pragma unroll
        for (int ww = 1; ww < 4; ++ww) m = fmaxf(m, spart[ww][ch >> 3][ch & 7]);
        out_feat[(size_t)bs * 128 + ch] = m;
      }
    }
  }
}

extern "C" void kernel_launch(void* const* d_in, const int* in_sizes, int n_in,
                              void* d_out, int out_size, void* d_ws, size_t ws_size,
                              hipStream_t stream) {
  const float* xyz  = (const float*)d_in[0];
  const float* feat = (const float*)d_in[1];
  const float* W1   = (const float*)d_in[2];
  const float* g1   = (const float*)d_in[3];
  const float* b1   = (const float*)d_in[4];
  const float* W2   = (const float*)d_in[5];
  const float* g2   = (const float*)d_in[6];
  const float* b2   = (const float*)d_in[7];
  float* out = (float*)d_out;
  float* new_xyz = out;                              // [4,2048,3]
  float* out_feat = out + NBATCH * N_SAMP * 3;       // [4,2048,128]

  int* fps_i = (int*)d_ws;                           // [8192]
  int* knn_i = fps_i + NBATCH * N_SAMP;              // [131072]
  float* stats1 = (float*)(knn_i + NROWS);           // [256]
  float* stats2 = stats1 + 256;                      // [256]
  float* y1 = stats2 + 256;                          // [131072*128]
  float* y2 = y1 + (size_t)NROWS * 128;              // [131072*128]

  const size_t need = (size_t)(NBATCH * N_SAMP) * 4 + (size_t)NROWS * 4 + 512 * 4 +
                      2ull * (size_t)NROWS * 128 * 4;

  hipMemsetAsync(stats1, 0, 512 * sizeof(float), stream);
  hipLaunchKernelGGL(fps_kernel, dim3(NBATCH), dim3(512), 0, stream, xyz, fps_i, new_xyz);
  hipLaunchKernelGGL(knn_kernel, dim3((NBATCH * N_SAMP) / 4), dim3(256), 0, stream,
                     xyz, new_xyz, knn_i);
  if (ws_size >= need) {
    hipLaunchKernelGGL(gemm1_kernel, dim3(NROWS / 128), dim3(256), 0, stream,
                       xyz, feat, W1, new_xyz, knn_i, y1, stats1);
    hipLaunchKernelGGL(gemm2_kernel, dim3(NROWS / 128), dim3(256), 0, stream,
                       y1, W2, stats1, g1, b1, y2, stats2);
    hipLaunchKernelGGL(pool_kernel, dim3(NBATCH * N_SAMP / 8), dim3(256), 0, stream,
                       y2, stats2, g2, b2, out_feat);
  } else {
    hipLaunchKernelGGL((mlp_kernel<0>), dim3(NBATCH * N_SAMP), dim3(256), 0, stream,
                       xyz, feat, W1, g1, b1, W2, g2, b2, new_xyz, knn_i, stats1, stats2, out_feat);
    hipLaunchKernelGGL((mlp_kernel<1>), dim3(NBATCH * N_SAMP), dim3(256), 0, stream,
                       xyz, feat, W1, g1, b1, W2, g2, b2, new_xyz, knn_i, stats1, stats2, out_feat);
    hipLaunchKernelGGL((mlp_kernel<2>), dim3(NBATCH * N_SAMP), dim3(256), 0, stream,
                       xyz, feat, W1, g1, b1, W2, g2, b2, new_xyz, knn_i, stats1, stats2, out_feat);
  }
}